// Round 1
// baseline (3289.872 us; speedup 1.0000x reference)
//
#include <hip/hip_runtime.h>
#include <math.h>

// Problem constants
#define HH 180
#define WW 360
#define CC 512
#define NBLK 8
#define BSZ 64
#define NPOS (HH*WW)           // 64800
#define PLANE (WW*CC)          // 184320 (per-h stride, also the idht norm)

// ---------------- cas matrices ----------------
// cas(n)[i][j] = cos(2*pi*i*j/n) + sin(2*pi*i*j/n); periodic in (i*j) mod n.
__global__ void fill_cas(float* __restrict__ casC, float* __restrict__ casW) {
    int idx = blockIdx.x * 256 + threadIdx.x;
    if (idx < CC*CC) {
        int c = idx >> 9, d = idx & (CC-1);
        int m = (c * d) & (CC-1);
        float a = (float)m * (6.283185307179586f / (float)CC);
        float s, co; __sincosf(a, &s, &co);
        casC[idx] = co + s;
    }
    if (idx < WW*WW) {
        int v = idx / WW, w = idx - v*WW;
        int m = (v * w) % WW;
        float a = (float)m * (6.283185307179586f / (float)WW);
        float s, co; __sincosf(a, &s, &co);
        casW[idx] = co + s;
    }
}

// ---------------- generic row-major fp32 GEMM ----------------
// C[m][n] = sum_k A[m][k] * B[k][n]; optional epilogue C = C*scale + Xadd.
// Batched via blockIdx.z with element strides sA/sB/sC (sX == sC for Xadd).
#define BM 128
#define BN 64
#define BK 16

__global__ __launch_bounds__(256)
void gemm_rrr(const float* __restrict__ A, long long sA,
              const float* __restrict__ Bmat, long long sB,
              float* __restrict__ Cm, long long sC,
              const float* __restrict__ Xadd, float scale,
              int M, int N, int K)
{
    __shared__ float As[BK][BM + 4];   // transposed A tile, padded
    __shared__ float Bs[BK][BN + 4];

    const int z = blockIdx.z;
    A    += sA * z;
    Bmat += sB * z;
    Cm   += sC * z;

    const int row0 = blockIdx.x * BM;
    const int col0 = blockIdx.y * BN;
    const int tid  = threadIdx.x;
    const int tx   = tid & 15;   // n dim
    const int ty   = tid >> 4;   // m dim

    float acc[8][4];
    #pragma unroll
    for (int i = 0; i < 8; ++i)
        #pragma unroll
        for (int j = 0; j < 4; ++j) acc[i][j] = 0.f;

    const int nK = (K + BK - 1) / BK;
    for (int kt = 0; kt < nK; ++kt) {
        const int k0 = kt * BK;
        // ---- stage A tile (BM x BK), transposed into As[k][m], zero-padded
        #pragma unroll
        for (int r = 0; r < 2; ++r) {
            int t  = tid + r * 256;
            int m  = t >> 2;
            int k4 = (t & 3) << 2;
            int gm = row0 + m, gk = k0 + k4;
            float4 v = make_float4(0.f, 0.f, 0.f, 0.f);
            if (gm < M) {
                if (gk + 4 <= K) {
                    v = *(const float4*)(A + (long long)gm * K + gk);
                } else if (gk < K) {
                    const float* ap = A + (long long)gm * K;
                    v.x = ap[gk];
                    if (gk + 1 < K) v.y = ap[gk + 1];
                    if (gk + 2 < K) v.z = ap[gk + 2];
                }
            }
            As[k4 + 0][m] = v.x; As[k4 + 1][m] = v.y;
            As[k4 + 2][m] = v.z; As[k4 + 3][m] = v.w;
        }
        // ---- stage B tile (BK x BN); N is always a multiple of BN here
        {
            int k  = tid >> 4;
            int n4 = (tid & 15) << 2;
            int gk = k0 + k;
            float4 v = make_float4(0.f, 0.f, 0.f, 0.f);
            if (gk < K) v = *(const float4*)(Bmat + (long long)gk * N + col0 + n4);
            *(float4*)&Bs[k][n4] = v;
        }
        __syncthreads();
        // ---- 8x4 microtile FMAs
        #pragma unroll
        for (int k = 0; k < BK; ++k) {
            float4 a0 = *(const float4*)&As[k][ty * 8];
            float4 a1 = *(const float4*)&As[k][ty * 8 + 4];
            float4 b0 = *(const float4*)&Bs[k][tx * 4];
            float a_[8] = {a0.x, a0.y, a0.z, a0.w, a1.x, a1.y, a1.z, a1.w};
            float b_[4] = {b0.x, b0.y, b0.z, b0.w};
            #pragma unroll
            for (int i = 0; i < 8; ++i)
                #pragma unroll
                for (int j = 0; j < 4; ++j)
                    acc[i][j] = fmaf(a_[i], b_[j], acc[i][j]);
        }
        __syncthreads();
    }
    // ---- epilogue
    #pragma unroll
    for (int i = 0; i < 8; ++i) {
        int gm = row0 + ty * 8 + i;
        if (gm >= M) continue;
        long long base = (long long)gm * N + col0 + tx * 4;
        if (Xadd) {
            const float* xp = Xadd + sC * z + base;
            float4 xo = *(const float4*)xp;
            float4 v = make_float4(fmaf(acc[i][0], scale, xo.x),
                                   fmaf(acc[i][1], scale, xo.y),
                                   fmaf(acc[i][2], scale, xo.z),
                                   fmaf(acc[i][3], scale, xo.w));
            *(float4*)(Cm + base) = v;
        } else {
            float4 v = make_float4(acc[i][0], acc[i][1], acc[i][2], acc[i][3]);
            *(float4*)(Cm + base) = v;
        }
    }
}

// ---------------- fused block-MLP + softshrink ----------------
// Per position p=(h,v) and block kb: xh row and xn row (negated index),
//   o1k = relu(0.5*(xh*w1a + xn*w1b) + b1[0])
//   o1n = relu(0.5*(xn*w1a + xh*w1b) + b1[1])
//   o2k = 0.5*(o1k*w2a + o1n*w2b) + b2[0]
//   o2n = 0.5*(o1n*w2a + o2k*w2b) + b2[1]   (source bug: consumes o2k)
//   out = softshrink(o2k + o2n, 0.01)
// 48 positions per WG; two weight phases so static LDS stays < 64 KB.
#define POSWG 48

__global__ __launch_bounds__(256)
void mlp_kernel(const float* __restrict__ xh,
                const float* __restrict__ w1, const float* __restrict__ b1,
                const float* __restrict__ w2, const float* __restrict__ b2,
                float* __restrict__ out)
{
    __shared__ float smem[15360];          // 60 KB
    float* wA   = smem;                    // 4096: w1a or w2a  [i][o]
    float* wB   = smem + 4096;             // 4096: w1b or w2b
    float* o1k  = smem + 8192;             // 48*64
    float* o1n  = smem + 11264;            // 48*64
    float* acts = smem + 14336;            // [2][4][64]
    float* o2ks = smem + 14848;            // [4][64]
    float* bs_  = smem + 15104;            // [4][64]

    const int kb  = blockIdx.y;
    const int tid = threadIdx.x;
    const int o   = tid & 63;
    const int q   = tid >> 6;
    const int p0  = blockIdx.x * POSWG;

    if (tid < 64) {
        bs_[0 * 64 + tid] = b1[kb * 64 + tid];
        bs_[1 * 64 + tid] = b1[NBLK * BSZ + kb * 64 + tid];
        bs_[2 * 64 + tid] = b2[kb * 64 + tid];
        bs_[3 * 64 + tid] = b2[NBLK * BSZ + kb * 64 + tid];
    }
    // phase-1 weights: w1a = w1[0]+w1[1], w1b = w1[0]-w1[1]
    {
        const float* wp0 = w1 + (long long)kb * 4096;
        const float* wp1 = w1 + 32768 + (long long)kb * 4096;
        for (int t = tid; t < 4096; t += 256) {
            float a = wp0[t], b = wp1[t];
            wA[t] = a + b; wB[t] = a - b;
        }
    }
    __syncthreads();

    // -------- layer 1 over all 48 positions --------
    for (int c = 0; c < POSWG / 4; ++c) {
        int lp = c * 4 + q;
        int p  = p0 + lp;
        {
            int h  = p / WW, v = p - h * WW;
            int hn = (h == 0) ? 0 : HH - h;
            int vn = (v == 0) ? 0 : WW - v;
            long long base  = (long long)p * CC + kb * 64;
            long long basen = (long long)(hn * WW + vn) * CC + kb * 64;
            acts[(0 * 4 + q) * 64 + o] = xh[base + o];
            acts[(1 * 4 + q) * 64 + o] = xh[basen + o];
        }
        __syncthreads();
        float ak = 0.f, bk = 0.f, an = 0.f, bn = 0.f;
        #pragma unroll 16
        for (int i = 0; i < 64; ++i) {
            float wa = wA[i * 64 + o], wb = wB[i * 64 + o];
            float xi = acts[(0 * 4 + q) * 64 + i];
            float ni = acts[(1 * 4 + q) * 64 + i];
            ak = fmaf(xi, wa, ak); bk = fmaf(ni, wb, bk);
            an = fmaf(ni, wa, an); bn = fmaf(xi, wb, bn);
        }
        o1k[lp * 64 + o] = fmaxf(fmaf(0.5f, ak + bk, bs_[o]), 0.f);
        o1n[lp * 64 + o] = fmaxf(fmaf(0.5f, an + bn, bs_[64 + o]), 0.f);
        __syncthreads();   // acts reused next chunk
    }

    // -------- swap in layer-2 weights --------
    {
        const float* wp0 = w2 + (long long)kb * 4096;
        const float* wp1 = w2 + 32768 + (long long)kb * 4096;
        for (int t = tid; t < 4096; t += 256) {
            float a = wp0[t], b = wp1[t];
            wA[t] = a + b; wB[t] = a - b;
        }
    }
    __syncthreads();

    // -------- layer 2 + softshrink --------
    for (int c = 0; c < POSWG / 4; ++c) {
        int lp = c * 4 + q;
        int p  = p0 + lp;
        float a2 = 0.f, c2 = 0.f;
        #pragma unroll 16
        for (int i = 0; i < 64; ++i) {
            a2 = fmaf(o1k[lp * 64 + i], wA[i * 64 + o], a2);
            c2 = fmaf(o1n[lp * 64 + i], wB[i * 64 + o], c2);
        }
        float v2k = fmaf(0.5f, a2 + c2, bs_[128 + o]);
        o2ks[q * 64 + o] = v2k;
        __syncthreads();
        float a3 = 0.f, b3 = 0.f;
        #pragma unroll 16
        for (int i = 0; i < 64; ++i) {
            a3 = fmaf(o1n[lp * 64 + i], wA[i * 64 + o], a3);
            b3 = fmaf(o2ks[q * 64 + i], wB[i * 64 + o], b3);
        }
        float y  = v2k + fmaf(0.5f, a3 + b3, bs_[192 + o]);
        float ay = fabsf(y) - 0.01f;   // softshrink lambda
        float r  = (ay > 0.f) ? ((y > 0.f) ? ay : -ay) : 0.f;
        out[(long long)p * CC + kb * 64 + o] = r;
        __syncthreads();   // o2ks reused next chunk
    }
}

// ---------------- launch ----------------
extern "C" void kernel_launch(void* const* d_in, const int* in_sizes, int n_in,
                              void* d_out, int out_size, void* d_ws, size_t ws_size,
                              hipStream_t stream) {
    const float* x  = (const float*)d_in[0];
    const float* w1 = (const float*)d_in[1];
    const float* b1 = (const float*)d_in[2];
    const float* w2 = (const float*)d_in[3];
    const float* b2 = (const float*)d_in[4];
    float* out = (float*)d_out;

    float* ws   = (float*)d_ws;
    float* casC = ws;                       // 262144 floats
    float* casW = ws + CC*CC;               // 129600 floats
    float* buf  = ws + CC*CC + WW*WW;       // 33,177,600 floats (pong buffer)

    // 0) cas matrices
    fill_cas<<<(CC*CC + 255) / 256, 256, 0, stream>>>(casC, casW);

    // 1) t1 = x · casC            (64800x512)·(512x512) -> out
    dim3 gBig((NPOS + BM - 1) / BM, CC / BN, 1);       // 507 x 8
    gemm_rrr<<<gBig, 256, 0, stream>>>(x, 0LL, casC, 0LL, out, 0LL,
                                       nullptr, 1.f, NPOS, CC, CC);

    // 2) xh[h] = casW · t1[h]     per-h (360x360)·(360x512) -> buf
    dim3 gBat((WW + BM - 1) / BM, CC / BN, HH);        // 3 x 8 x 180
    gemm_rrr<<<gBat, 256, 0, stream>>>(casW, 0LL, out, (long long)PLANE,
                                       buf, (long long)PLANE,
                                       nullptr, 1.f, WW, CC, WW);

    // 3) fused block-MLP + softshrink: buf -> out
    dim3 gMlp(NPOS / POSWG, NBLK, 1);                  // 1350 x 8
    mlp_kernel<<<gMlp, 256, 0, stream>>>(buf, w1, b1, w2, b2, out);

    // 4) t2 = s · casC -> buf
    gemm_rrr<<<gBig, 256, 0, stream>>>(out, 0LL, casC, 0LL, buf, 0LL,
                                       nullptr, 1.f, NPOS, CC, CC);

    // 5) out[h] = (casW · t2[h]) / (W*C) + x[h]
    gemm_rrr<<<gBat, 256, 0, stream>>>(casW, 0LL, buf, (long long)PLANE,
                                       out, (long long)PLANE,
                                       x, 1.0f / (float)PLANE, WW, CC, WW);
}

// Round 2
// 895.384 us; speedup vs baseline: 3.6743x; 3.6743x over previous
//
#include <hip/hip_runtime.h>
#include <math.h>

// Problem constants
#define HH 180
#define WDIM 360
#define CDIM 512
#define NP 64800           // 180*360 positions
#define PL 184320          // 360*512 per-h plane (also idht norm)

typedef unsigned short u16;
typedef __attribute__((ext_vector_type(8))) short short8;  // 8 bf16 = 4 VGPR
typedef __attribute__((ext_vector_type(4))) float f4;      // 4 fp32 acc

__device__ __forceinline__ u16 f2bf(float f){
    unsigned u = __float_as_uint(f);
    return (u16)((u + 0x7fffu + ((u >> 16) & 1u)) >> 16);   // RNE
}
__device__ __forceinline__ void gl_lds16(const void* g, void* l){
    __builtin_amdgcn_global_load_lds((const __attribute__((address_space(1))) void*)g,
                                     (__attribute__((address_space(3))) void*)l, 16, 0, 0);
}

// ---------------- prep: cas matrices (bf16) + folded transposed weights ----------------
// casC [512][512] (symmetric); casW [360][384] (cols >=360 zero, K padded to 384)
// wts = [w1a_t, w1b_t, w2a_t, w2b_t], each [8][64(out o)][64(in i)], 0.5 folded in.
__global__ void prep(const float* __restrict__ w1, const float* __restrict__ w2,
                     u16* __restrict__ casC, u16* __restrict__ casW, u16* __restrict__ wts)
{
    int idx = blockIdx.x * 256 + threadIdx.x;
    if (idx < 512*512){
        int i = idx >> 9, j = idx & 511;
        int m = (i * j) & 511;                       // exact angle reduction
        float a = (float)m * (6.283185307179586f / 512.0f);
        float s, c; __sincosf(a, &s, &c);
        casC[idx] = f2bf(c + s);
    }
    if (idx < 360*384){
        int i = idx / 384, j = idx - (idx / 384) * 384;
        u16 v = 0;
        if (j < 360){
            int m = (i * j) % 360;
            float a = (float)m * (6.283185307179586f / 360.0f);
            float s, c; __sincosf(a, &s, &c);
            v = f2bf(c + s);
        }
        casW[idx] = v;
    }
    if (idx < 131072){
        int s = idx >> 15, r = idx & 32767;
        int kb = r >> 12, o = (r >> 6) & 63, ii = r & 63;
        const float* w = (s < 2) ? w1 : w2;
        float v0 = w[kb*4096 + ii*64 + o];
        float v1 = w[32768 + kb*4096 + ii*64 + o];
        float v = 0.5f * ((s & 1) ? (v0 - v1) : (v0 + v1));
        wts[idx] = f2bf(v);
    }
}

// ---------------- MFMA GEMM: C(Mx512) = A(MxK) * B(Kx512) ----------------
// 128x128 tile, 4 waves, 16 MFMA + 8 ds_read_b128 per 32-K step (m97 structure).
// A always bf16 row-major [m][k], staged via global_load_lds (rows clamped to clampA).
// BST=0: B given as B^T bf16 [n][k] (casC symmetric), staged via global_load_lds.
// BST=1: B given as fp32 [k][n] (x) -> transposed+converted in LDS (k>=Kreal -> 0).
// BST=2: B given as bf16 [k][n] (z) -> transposed in LDS.
// EPI=0: store bf16. EPI=1: store fp32 = acc*scale + X (residual add).
template<int BST, int EPI>
__global__ __launch_bounds__(256)
void gemm_k(const u16* __restrict__ A, int ldA, long long sA, int clampA,
            const void* __restrict__ B, int ldB, long long sB,
            void* __restrict__ C, long long sC, int Mreal,
            const float* __restrict__ X, float scale,
            int nK, int Kreal)
{
    __shared__ u16 As[4096];   // [128][32] bf16, 64 B rows
    __shared__ u16 Bs[4096];   // [128 n][32 k]

    const int tid = threadIdx.x, wv = tid >> 6, l = tid & 63;
    const int lane16 = l & 15, quad = l >> 4;
    const int z = blockIdx.z;
    const int row0 = blockIdx.x * 128, col0 = blockIdx.y * 128;

    const u16* Az = A + sA * z;
    int ra0 = row0 + wv*32 + (l >> 2); int ra1 = ra0 + 16;
    ra0 = ra0 <= clampA ? ra0 : clampA;
    ra1 = ra1 <= clampA ? ra1 : clampA;
    const u16* gA0 = Az + (long long)ra0 * ldA + (l & 3) * 8;
    const u16* gA1 = Az + (long long)ra1 * ldA + (l & 3) * 8;
    u16* lA0 = As + wv*1024 + l*8;
    u16* lA1 = lA0 + 512;

    const u16* gB0 = nullptr; const u16* gB1 = nullptr;
    u16* lB0 = nullptr; u16* lB1 = nullptr;
    const float* Bzf = nullptr; const u16* Bzh = nullptr;
    if constexpr (BST == 0){
        const u16* Bz = (const u16*)B + sB * z;
        int rb0 = col0 + wv*32 + (l >> 2); int rb1 = rb0 + 16;
        gB0 = Bz + (long long)rb0 * ldB + (l & 3) * 8;
        gB1 = Bz + (long long)rb1 * ldB + (l & 3) * 8;
        lB0 = Bs + wv*1024 + l*8;
        lB1 = lB0 + 512;
    }
    if constexpr (BST == 1) Bzf = (const float*)B + sB * z;
    if constexpr (BST == 2) Bzh = (const u16*)B + sB * z;

    f4 acc[4][4];
    #pragma unroll
    for (int mt = 0; mt < 4; ++mt)
        #pragma unroll
        for (int nt = 0; nt < 4; ++nt)
            acc[mt][nt] = (f4)0.0f;

    const int mrow = (wv >> 1) * 64, ncol = (wv & 1) * 64;

    for (int kt = 0; kt < nK; ++kt){
        const int k0 = kt * 32;
        gl_lds16(gA0 + k0, lA0);
        gl_lds16(gA1 + k0, lA1);
        if constexpr (BST == 0){
            gl_lds16(gB0 + k0, lB0);
            gl_lds16(gB1 + k0, lB1);
        } else {
            // transpose-stage: lane owns one column c, 16 k's; writes are 2-way (free)
            const int c = tid & 127, kh = (tid >> 7) * 16;
            u16 hv[16];
            #pragma unroll
            for (int kk = 0; kk < 16; ++kk){
                int k = k0 + kh + kk;
                u16 h = 0;
                if (k < Kreal){
                    if constexpr (BST == 1) h = f2bf(Bzf[(long long)k * 512 + col0 + c]);
                    else                    h = Bzh[(long long)k * 512 + col0 + c];
                }
                hv[kk] = h;
            }
            #pragma unroll
            for (int j = 0; j < 8; ++j){
                unsigned wrd = (unsigned)hv[2*j] | ((unsigned)hv[2*j+1] << 16);
                *(unsigned*)&Bs[c*32 + kh + 2*j] = wrd;
            }
        }
        __syncthreads();
        short8 af[4];
        #pragma unroll
        for (int mt = 0; mt < 4; ++mt)
            af[mt] = *(const short8*)&As[(mrow + mt*16 + lane16)*32 + quad*8];
        #pragma unroll
        for (int nt = 0; nt < 4; ++nt){
            short8 bfv = *(const short8*)&Bs[(ncol + nt*16 + lane16)*32 + quad*8];
            #pragma unroll
            for (int mt = 0; mt < 4; ++mt)
                acc[mt][nt] = __builtin_amdgcn_mfma_f32_16x16x32_bf16(af[mt], bfv, acc[mt][nt], 0, 0, 0);
        }
        __syncthreads();
    }

    // epilogue: C/D layout col=lane&15, row=quad*4+reg
    #pragma unroll
    for (int mt = 0; mt < 4; ++mt){
        #pragma unroll
        for (int nt = 0; nt < 4; ++nt){
            int gc = col0 + ncol + nt*16 + lane16;
            #pragma unroll
            for (int i = 0; i < 4; ++i){
                int gr = row0 + mrow + mt*16 + quad*4 + i;
                if (gr < Mreal){
                    long long off = (long long)gr * 512 + gc;
                    if constexpr (EPI == 0){
                        ((u16*)C)[sC*z + off] = f2bf(acc[mt][nt][i]);
                    } else {
                        ((float*)C)[sC*z + off] = fmaf(acc[mt][nt][i], scale, X[sC*z + off]);
                    }
                }
            }
        }
    }
}

// ---------------- MFMA block-MLP + softshrink ----------------
// Per (64-position tile, block kb): o1k/o1n -> o2k -> o2n -> softshrink(o2k+o2n).
// Weights pre-folded (0.5 in) and transposed [o][i] in ws. LDS stride 72 (bank spread).
__global__ __launch_bounds__(256)
void mlp_k(const u16* __restrict__ xh, const u16* __restrict__ wts,
           const float* __restrict__ b1, const float* __restrict__ b2,
           u16* __restrict__ yout)
{
    __shared__ u16 sW0[64*72], sW1[64*72];
    __shared__ u16 sXh[64*72], sXn[64*72], s1k[64*72], s1n[64*72];
    __shared__ float sb[256];

    const int tid = threadIdx.x;
    const int wv = tid >> 6, l = tid & 63, lane16 = l & 15, quad = l >> 4;
    const int kb = blockIdx.y;
    const int p0 = blockIdx.x * 64;
    const int w16 = wv * 16;

    if (tid < 64){
        sb[tid]       = b1[kb*64 + tid];
        sb[64 + tid]  = b1[512 + kb*64 + tid];
        sb[128 + tid] = b2[kb*64 + tid];
        sb[192 + tid] = b2[512 + kb*64 + tid];
    }
    {
        const int r = tid >> 2, sg = (tid & 3) * 16;
        const u16* s0 = wts + kb*4096 + r*64 + sg;            // w1a_t
        const u16* s1 = wts + 32768 + kb*4096 + r*64 + sg;    // w1b_t
        *(uint4*)&sW0[r*72 + sg]     = *(const uint4*)s0;
        *(uint4*)&sW0[r*72 + sg + 8] = *(const uint4*)(s0 + 8);
        *(uint4*)&sW1[r*72 + sg]     = *(const uint4*)s1;
        *(uint4*)&sW1[r*72 + sg + 8] = *(const uint4*)(s1 + 8);

        int p = p0 + r; int pc = p <= 64799 ? p : 64799;
        int h = pc / 360; int v = pc - h * 360;
        int hn = (h == 0) ? 0 : (180 - h);
        int vn = (v == 0) ? 0 : (360 - v);
        long long bh = (long long)pc * 512 + kb*64 + sg;
        long long bn = (long long)(hn*360 + vn) * 512 + kb*64 + sg;
        *(uint4*)&sXh[r*72 + sg]     = *(const uint4*)&xh[bh];
        *(uint4*)&sXh[r*72 + sg + 8] = *(const uint4*)&xh[bh + 8];
        *(uint4*)&sXn[r*72 + sg]     = *(const uint4*)&xh[bn];
        *(uint4*)&sXn[r*72 + sg + 8] = *(const uint4*)&xh[bn + 8];
    }
    __syncthreads();

    // -------- layer 1 --------
    f4 aK[4], aN[4];
    #pragma unroll
    for (int nt = 0; nt < 4; ++nt){ aK[nt] = (f4)0.0f; aN[nt] = (f4)0.0f; }
    #pragma unroll
    for (int kq = 0; kq < 2; ++kq){
        short8 fxh = *(const short8*)&sXh[(w16 + lane16)*72 + kq*32 + quad*8];
        short8 fxn = *(const short8*)&sXn[(w16 + lane16)*72 + kq*32 + quad*8];
        #pragma unroll
        for (int nt = 0; nt < 4; ++nt){
            short8 wa = *(const short8*)&sW0[(nt*16 + lane16)*72 + kq*32 + quad*8];
            short8 wb = *(const short8*)&sW1[(nt*16 + lane16)*72 + kq*32 + quad*8];
            aK[nt] = __builtin_amdgcn_mfma_f32_16x16x32_bf16(fxh, wa, aK[nt], 0,0,0);
            aK[nt] = __builtin_amdgcn_mfma_f32_16x16x32_bf16(fxn, wb, aK[nt], 0,0,0);
            aN[nt] = __builtin_amdgcn_mfma_f32_16x16x32_bf16(fxn, wa, aN[nt], 0,0,0);
            aN[nt] = __builtin_amdgcn_mfma_f32_16x16x32_bf16(fxh, wb, aN[nt], 0,0,0);
        }
    }
    #pragma unroll
    for (int nt = 0; nt < 4; ++nt){
        int cc = nt*16 + lane16;
        #pragma unroll
        for (int i = 0; i < 4; ++i){
            int rr = w16 + quad*4 + i;
            float vk = fmaxf(aK[nt][i] + sb[cc], 0.f);
            float vn = fmaxf(aN[nt][i] + sb[64 + cc], 0.f);
            s1k[rr*72 + cc] = f2bf(vk);
            s1n[rr*72 + cc] = f2bf(vn);
        }
    }
    __syncthreads();

    // -------- swap weights to layer 2 --------
    {
        const int r = tid >> 2, sg = (tid & 3) * 16;
        const u16* s0 = wts + 65536 + kb*4096 + r*64 + sg;    // w2a_t
        const u16* s1 = wts + 98304 + kb*4096 + r*64 + sg;    // w2b_t
        *(uint4*)&sW0[r*72 + sg]     = *(const uint4*)s0;
        *(uint4*)&sW0[r*72 + sg + 8] = *(const uint4*)(s0 + 8);
        *(uint4*)&sW1[r*72 + sg]     = *(const uint4*)s1;
        *(uint4*)&sW1[r*72 + sg + 8] = *(const uint4*)(s1 + 8);
    }
    __syncthreads();

    // -------- layer 2a: o2k --------
    f4 k2[4];
    #pragma unroll
    for (int nt = 0; nt < 4; ++nt) k2[nt] = (f4)0.0f;
    #pragma unroll
    for (int kq = 0; kq < 2; ++kq){
        short8 a1k = *(const short8*)&s1k[(w16 + lane16)*72 + kq*32 + quad*8];
        short8 a1n = *(const short8*)&s1n[(w16 + lane16)*72 + kq*32 + quad*8];
        #pragma unroll
        for (int nt = 0; nt < 4; ++nt){
            short8 wa = *(const short8*)&sW0[(nt*16 + lane16)*72 + kq*32 + quad*8];
            short8 wb = *(const short8*)&sW1[(nt*16 + lane16)*72 + kq*32 + quad*8];
            k2[nt] = __builtin_amdgcn_mfma_f32_16x16x32_bf16(a1k, wa, k2[nt], 0,0,0);
            k2[nt] = __builtin_amdgcn_mfma_f32_16x16x32_bf16(a1n, wb, k2[nt], 0,0,0);
        }
    }
    #pragma unroll
    for (int nt = 0; nt < 4; ++nt){
        int cc = nt*16 + lane16;
        #pragma unroll
        for (int i = 0; i < 4; ++i){
            int rr = w16 + quad*4 + i;
            float v2 = k2[nt][i] + sb[128 + cc];
            k2[nt][i] = v2;                        // keep o2k (with bias) in regs
            sXh[rr*72 + cc] = f2bf(v2);            // reuse sXh as o2k A-operand
        }
    }
    __syncthreads();

    // -------- layer 2b: o2n (consumes o2k per source bug) + softshrink --------
    f4 n2[4];
    #pragma unroll
    for (int nt = 0; nt < 4; ++nt) n2[nt] = (f4)0.0f;
    #pragma unroll
    for (int kq = 0; kq < 2; ++kq){
        short8 a1n = *(const short8*)&s1n[(w16 + lane16)*72 + kq*32 + quad*8];
        short8 a2k = *(const short8*)&sXh[(w16 + lane16)*72 + kq*32 + quad*8];
        #pragma unroll
        for (int nt = 0; nt < 4; ++nt){
            short8 wa = *(const short8*)&sW0[(nt*16 + lane16)*72 + kq*32 + quad*8];
            short8 wb = *(const short8*)&sW1[(nt*16 + lane16)*72 + kq*32 + quad*8];
            n2[nt] = __builtin_amdgcn_mfma_f32_16x16x32_bf16(a1n, wa, n2[nt], 0,0,0);
            n2[nt] = __builtin_amdgcn_mfma_f32_16x16x32_bf16(a2k, wb, n2[nt], 0,0,0);
        }
    }
    #pragma unroll
    for (int nt = 0; nt < 4; ++nt){
        int cc = nt*16 + lane16;
        #pragma unroll
        for (int i = 0; i < 4; ++i){
            int rr = w16 + quad*4 + i;
            int p = p0 + rr;
            float y = k2[nt][i] + n2[nt][i] + sb[192 + cc];
            float ay = fabsf(y) - 0.01f;           // softshrink lambda
            float r0 = ay > 0.f ? (y > 0.f ? ay : -ay) : 0.f;
            if (p < 64800) yout[(long long)p * 512 + kb*64 + cc] = f2bf(r0);
        }
    }
}

// ---------------- launch ----------------
extern "C" void kernel_launch(void* const* d_in, const int* in_sizes, int n_in,
                              void* d_out, int out_size, void* d_ws, size_t ws_size,
                              hipStream_t stream) {
    const float* x  = (const float*)d_in[0];
    const float* w1 = (const float*)d_in[1];
    const float* b1 = (const float*)d_in[2];
    const float* w2 = (const float*)d_in[3];
    const float* b2 = (const float*)d_in[4];
    float* out = (float*)d_out;

    u16* ws   = (u16*)d_ws;
    u16* casC = ws;                        // 262144
    u16* casW = casC + 262144;             // 360*384 = 138240
    u16* wts  = casW + 138240;             // 131072
    u16* bufU = wts  + 131072;             // 64800*512 (u -> y)
    u16* bufX = bufU + 33177600;           // 64800*512 (xh -> z)
    // total ws: ~133.8 MB

    prep<<<1024, 256, 0, stream>>>(w1, w2, casC, casW, wts);

    dim3 gA(3, 4, 180), gB(507, 4, 1), gM(1013, 8, 1);

    // 1) u[h] = casW * x[h]           (W-contraction first; commutes with C)
    gemm_k<1,0><<<gA, 256, 0, stream>>>(casW, 384, 0, 359,
                                        x, 512, (long long)PL,
                                        bufU, (long long)PL, 360,
                                        nullptr, 0.f, 12, 360);
    // 2) xh = u * casC
    gemm_k<0,0><<<gB, 256, 0, stream>>>(bufU, 512, 0, 64799,
                                        casC, 512, 0,
                                        bufX, 0, 64800,
                                        nullptr, 0.f, 16, 512);
    // 3) block-MLP + softshrink: xh -> y (bufU)
    mlp_k<<<gM, 256, 0, stream>>>(bufX, wts, b1, b2, bufU);
    // 4) z = y * casC
    gemm_k<0,0><<<gB, 256, 0, stream>>>(bufU, 512, 0, 64799,
                                        casC, 512, 0,
                                        bufX, 0, 64800,
                                        nullptr, 0.f, 16, 512);
    // 5) out[h] = (casW * z[h]) / 184320 + x[h]
    gemm_k<2,1><<<gA, 256, 0, stream>>>(casW, 384, 0, 359,
                                        bufX, 512, (long long)PL,
                                        out, (long long)PL, 360,
                                        x, 1.0f/184320.0f, 12, 360);
}

// Round 3
// 719.650 us; speedup vs baseline: 4.5715x; 1.2442x over previous
//
#include <hip/hip_runtime.h>
#include <math.h>

// Problem constants
#define HH 180
#define WDIM 360
#define CDIM 512
#define NP 64800           // 180*360 positions
#define PL 184320          // 360*512 per-h plane (also idht norm)

typedef unsigned short u16;
typedef __attribute__((ext_vector_type(8))) short short8;  // 8 bf16 = 4 VGPR
typedef __attribute__((ext_vector_type(4))) float f4;      // 4 fp32 acc

__device__ __forceinline__ u16 f2bf(float f){
    unsigned u = __float_as_uint(f);
    return (u16)((u + 0x7fffu + ((u >> 16) & 1u)) >> 16);   // RNE
}
__device__ __forceinline__ void gl_lds16(const void* g, void* l){
    __builtin_amdgcn_global_load_lds((const __attribute__((address_space(1))) void*)g,
                                     (__attribute__((address_space(3))) void*)l, 16, 0, 0);
}

// ---------------- prep: cas matrices (bf16) + folded transposed weights ----------------
// casC [512][512] (symmetric); casW [360][384] (cols >=360 ZERO -> kills k-overread)
// wts = [w1a_t, w1b_t, w2a_t, w2b_t], each [8][64 o][64 i], 0.5 folded in.
__global__ void prep(const float* __restrict__ w1, const float* __restrict__ w2,
                     u16* __restrict__ casC, u16* __restrict__ casW, u16* __restrict__ wts)
{
    int idx = blockIdx.x * 256 + threadIdx.x;
    if (idx < 512*512){
        int i = idx >> 9, j = idx & 511;
        int m = (i * j) & 511;                       // exact angle reduction
        float a = (float)m * (6.283185307179586f / 512.0f);
        float s, c; __sincosf(a, &s, &c);
        casC[idx] = f2bf(c + s);
    }
    if (idx < 360*384){
        int i = idx / 384, j = idx - (idx / 384) * 384;
        u16 v = 0;
        if (j < 360){
            int m = (i * j) % 360;
            float a = (float)m * (6.283185307179586f / 360.0f);
            float s, c; __sincosf(a, &s, &c);
            v = f2bf(c + s);
        }
        casW[idx] = v;
    }
    if (idx < 131072){
        int s = idx >> 15, r = idx & 32767;
        int kb = r >> 12, o = (r >> 6) & 63, ii = r & 63;
        const float* w = (s < 2) ? w1 : w2;
        float v0 = w[kb*4096 + ii*64 + o];
        float v1 = w[32768 + kb*4096 + ii*64 + o];
        float v = 0.5f * ((s & 1) ? (v0 - v1) : (v0 + v1));
        wts[idx] = f2bf(v);
    }
}

// ---------------- MFMA GEMM: C(Mx512) = A(MxK) * B^T(512xK) ----------------
// 128x128 tile, 4 waves. LDS layout is k-chunk-major [4 chunks][128 rows][8 u16]
// -> every sequential 8-lane ds_read_b128 phase hits all 32 banks (conflict-free),
// and still stages as 8 contiguous 1KB global_load_lds segments per operand.
// ASTAGE=0: A bf16 [m][k] via global_load_lds. ASTAGE=1: A fp32 [m][k], staged
//   via float4 loads + bf16 pack + ds_write_b128.
// B always bf16 [n][k] rows via global_load_lds (over-read past k=K is harmless:
//   A-side zeros or buffer pad).
// STORE=0: bf16 [m][512]. STORE=1: bf16 transposed T[h][d][w] (m=(h,w), n=d).
// STORE=2: fp32 [m][512] = acc*scale + X (residual).
template<int ASTAGE, int STORE, int SWAP>
__global__ __launch_bounds__(256)
void gemm_k(const void* __restrict__ A, int ldA, long long sA, int clampA,
            const u16* __restrict__ B, int ldB, long long sB,
            void* __restrict__ C, long long sC, int Mreal,
            const float* __restrict__ X, float scale, int nK)
{
    __shared__ u16 As[4096];   // [4][128][8]
    __shared__ u16 Bs[4096];

    const int tid = threadIdx.x, wv = tid >> 6, l = tid & 63;
    const int l16 = l & 15, quad = l >> 4;
    const int z = blockIdx.z;
    const int bx = SWAP ? blockIdx.y : blockIdx.x;
    const int by = SWAP ? blockIdx.x : blockIdx.y;
    const int row0 = bx * 128, col0 = by * 128;

    // wave w stages row-half rh = w&1, chunks {w>>1, w>>1+2} of each operand
    const int rh = wv & 1, c0 = wv >> 1;

    const u16* gB = B + sB * z + (long long)(col0 + rh*64 + l) * ldB;
    u16* lB0 = Bs + c0*1024 + rh*512;
    u16* lB1 = lB0 + 2048;

    const u16* gA = nullptr; u16* lA0 = nullptr; u16* lA1 = nullptr;
    const float* gAf = nullptr; int arow = 0;
    if constexpr (ASTAGE == 0){
        int r = row0 + rh*64 + l; r = r <= clampA ? r : clampA;
        gA  = (const u16*)A + sA * z + (long long)r * ldA;
        lA0 = As + c0*1024 + rh*512;
        lA1 = lA0 + 2048;
    } else {
        int r = row0 + (tid >> 1); r = r <= clampA ? r : clampA;
        gAf  = (const float*)A + (long long)r * ldA + (tid & 1) * 16;
        arow = tid >> 1;
    }

    f4 acc[4][4];
    #pragma unroll
    for (int mt = 0; mt < 4; ++mt)
        #pragma unroll
        for (int nt = 0; nt < 4; ++nt)
            acc[mt][nt] = (f4)0.0f;

    const int mrow = (wv >> 1) * 64, ncol = (wv & 1) * 64;

    for (int kt = 0; kt < nK; ++kt){
        const int k0 = kt * 32;
        gl_lds16(gB + k0 + c0*8,     lB0);
        gl_lds16(gB + k0 + (c0+2)*8, lB1);
        if constexpr (ASTAGE == 0){
            gl_lds16(gA + k0 + c0*8,     lA0);
            gl_lds16(gA + k0 + (c0+2)*8, lA1);
        } else {
            const float* p = gAf + k0;
            float4 f0 = *(const float4*)(p);
            float4 f1 = *(const float4*)(p + 4);
            float4 f2 = *(const float4*)(p + 8);
            float4 f3 = *(const float4*)(p + 12);
            uint4 w0, w1;
            w0.x = (unsigned)f2bf(f0.x) | ((unsigned)f2bf(f0.y) << 16);
            w0.y = (unsigned)f2bf(f0.z) | ((unsigned)f2bf(f0.w) << 16);
            w0.z = (unsigned)f2bf(f1.x) | ((unsigned)f2bf(f1.y) << 16);
            w0.w = (unsigned)f2bf(f1.z) | ((unsigned)f2bf(f1.w) << 16);
            w1.x = (unsigned)f2bf(f2.x) | ((unsigned)f2bf(f2.y) << 16);
            w1.y = (unsigned)f2bf(f2.z) | ((unsigned)f2bf(f2.w) << 16);
            w1.z = (unsigned)f2bf(f3.x) | ((unsigned)f2bf(f3.y) << 16);
            w1.w = (unsigned)f2bf(f3.z) | ((unsigned)f2bf(f3.w) << 16);
            const int cb = (tid & 1) * 2;
            *(uint4*)&As[cb*1024       + arow*8] = w0;
            *(uint4*)&As[(cb+1)*1024   + arow*8] = w1;
        }
        __syncthreads();
        short8 af[4];
        #pragma unroll
        for (int mt = 0; mt < 4; ++mt)
            af[mt] = *(const short8*)&As[quad*1024 + (mrow + mt*16 + l16)*8];
        #pragma unroll
        for (int nt = 0; nt < 4; ++nt){
            short8 bfv = *(const short8*)&Bs[quad*1024 + (ncol + nt*16 + l16)*8];
            #pragma unroll
            for (int mt = 0; mt < 4; ++mt)
                acc[mt][nt] = __builtin_amdgcn_mfma_f32_16x16x32_bf16(af[mt], bfv, acc[mt][nt], 0, 0, 0);
        }
        __syncthreads();
    }

    // epilogue: C/D layout col=lane&15, row=quad*4+reg
    #pragma unroll
    for (int mt = 0; mt < 4; ++mt){
        #pragma unroll
        for (int i = 0; i < 4; ++i){
            int gr = row0 + mrow + mt*16 + quad*4 + i;
            if (gr >= Mreal) continue;
            int th = 0, tw = 0;
            if constexpr (STORE == 1){ th = gr / 360; tw = gr - th * 360; }
            #pragma unroll
            for (int nt = 0; nt < 4; ++nt){
                int gc = col0 + ncol + nt*16 + l16;
                if constexpr (STORE == 0){
                    ((u16*)C)[sC*z + (long long)gr*512 + gc] = f2bf(acc[mt][nt][i]);
                } else if constexpr (STORE == 1){
                    ((u16*)C)[((long long)th*512 + gc)*360 + tw] = f2bf(acc[mt][nt][i]);
                } else {
                    long long off = sC*z + (long long)gr*512 + gc;
                    ((float*)C)[off] = fmaf(acc[mt][nt][i], scale, X[off]);
                }
            }
        }
    }
}

// ---------------- MFMA block-MLP + softshrink ----------------
__global__ __launch_bounds__(256)
void mlp_k(const u16* __restrict__ xh, const u16* __restrict__ wts,
           const float* __restrict__ b1, const float* __restrict__ b2,
           u16* __restrict__ yout)
{
    __shared__ u16 sW0[64*72], sW1[64*72];
    __shared__ u16 sXh[64*72], sXn[64*72], s1k[64*72], s1n[64*72];
    __shared__ float sb[256];

    const int tid = threadIdx.x;
    const int wv = tid >> 6, l = tid & 63, lane16 = l & 15, quad = l >> 4;
    const int kb = blockIdx.y;
    const int p0 = blockIdx.x * 64;
    const int w16 = wv * 16;

    if (tid < 64){
        sb[tid]       = b1[kb*64 + tid];
        sb[64 + tid]  = b1[512 + kb*64 + tid];
        sb[128 + tid] = b2[kb*64 + tid];
        sb[192 + tid] = b2[512 + kb*64 + tid];
    }
    {
        const int r = tid >> 2, sg = (tid & 3) * 16;
        const u16* s0 = wts + kb*4096 + r*64 + sg;            // w1a_t
        const u16* s1 = wts + 32768 + kb*4096 + r*64 + sg;    // w1b_t
        *(uint4*)&sW0[r*72 + sg]     = *(const uint4*)s0;
        *(uint4*)&sW0[r*72 + sg + 8] = *(const uint4*)(s0 + 8);
        *(uint4*)&sW1[r*72 + sg]     = *(const uint4*)s1;
        *(uint4*)&sW1[r*72 + sg + 8] = *(const uint4*)(s1 + 8);

        int p = p0 + r; int pc = p <= 64799 ? p : 64799;
        int h = pc / 360; int v = pc - h * 360;
        int hn = (h == 0) ? 0 : (180 - h);
        int vn = (v == 0) ? 0 : (360 - v);
        long long bh = (long long)pc * 512 + kb*64 + sg;
        long long bn = (long long)(hn*360 + vn) * 512 + kb*64 + sg;
        *(uint4*)&sXh[r*72 + sg]     = *(const uint4*)&xh[bh];
        *(uint4*)&sXh[r*72 + sg + 8] = *(const uint4*)&xh[bh + 8];
        *(uint4*)&sXn[r*72 + sg]     = *(const uint4*)&xh[bn];
        *(uint4*)&sXn[r*72 + sg + 8] = *(const uint4*)&xh[bn + 8];
    }
    __syncthreads();

    // -------- layer 1 --------
    f4 aK[4], aN[4];
    #pragma unroll
    for (int nt = 0; nt < 4; ++nt){ aK[nt] = (f4)0.0f; aN[nt] = (f4)0.0f; }
    #pragma unroll
    for (int kq = 0; kq < 2; ++kq){
        short8 fxh = *(const short8*)&sXh[(w16 + lane16)*72 + kq*32 + quad*8];
        short8 fxn = *(const short8*)&sXn[(w16 + lane16)*72 + kq*32 + quad*8];
        #pragma unroll
        for (int nt = 0; nt < 4; ++nt){
            short8 wa = *(const short8*)&sW0[(nt*16 + lane16)*72 + kq*32 + quad*8];
            short8 wb = *(const short8*)&sW1[(nt*16 + lane16)*72 + kq*32 + quad*8];
            aK[nt] = __builtin_amdgcn_mfma_f32_16x16x32_bf16(fxh, wa, aK[nt], 0,0,0);
            aK[nt] = __builtin_amdgcn_mfma_f32_16x16x32_bf16(fxn, wb, aK[nt], 0,0,0);
            aN[nt] = __builtin_amdgcn_mfma_f32_16x16x32_bf16(fxn, wa, aN[nt], 0,0,0);
            aN[nt] = __builtin_amdgcn_mfma_f32_16x16x32_bf16(fxh, wb, aN[nt], 0,0,0);
        }
    }
    #pragma unroll
    for (int nt = 0; nt < 4; ++nt){
        int cc = nt*16 + lane16;
        #pragma unroll
        for (int i = 0; i < 4; ++i){
            int rr = w16 + quad*4 + i;
            float vk = fmaxf(aK[nt][i] + sb[cc], 0.f);
            float vn = fmaxf(aN[nt][i] + sb[64 + cc], 0.f);
            s1k[rr*72 + cc] = f2bf(vk);
            s1n[rr*72 + cc] = f2bf(vn);
        }
    }
    __syncthreads();

    // -------- swap weights to layer 2 --------
    {
        const int r = tid >> 2, sg = (tid & 3) * 16;
        const u16* s0 = wts + 65536 + kb*4096 + r*64 + sg;    // w2a_t
        const u16* s1 = wts + 98304 + kb*4096 + r*64 + sg;    // w2b_t
        *(uint4*)&sW0[r*72 + sg]     = *(const uint4*)s0;
        *(uint4*)&sW0[r*72 + sg + 8] = *(const uint4*)(s0 + 8);
        *(uint4*)&sW1[r*72 + sg]     = *(const uint4*)s1;
        *(uint4*)&sW1[r*72 + sg + 8] = *(const uint4*)(s1 + 8);
    }
    __syncthreads();

    // -------- layer 2a: o2k --------
    f4 k2[4];
    #pragma unroll
    for (int nt = 0; nt < 4; ++nt) k2[nt] = (f4)0.0f;
    #pragma unroll
    for (int kq = 0; kq < 2; ++kq){
        short8 a1k = *(const short8*)&s1k[(w16 + lane16)*72 + kq*32 + quad*8];
        short8 a1n = *(const short8*)&s1n[(w16 + lane16)*72 + kq*32 + quad*8];
        #pragma unroll
        for (int nt = 0; nt < 4; ++nt){
            short8 wa = *(const short8*)&sW0[(nt*16 + lane16)*72 + kq*32 + quad*8];
            short8 wb = *(const short8*)&sW1[(nt*16 + lane16)*72 + kq*32 + quad*8];
            k2[nt] = __builtin_amdgcn_mfma_f32_16x16x32_bf16(a1k, wa, k2[nt], 0,0,0);
            k2[nt] = __builtin_amdgcn_mfma_f32_16x16x32_bf16(a1n, wb, k2[nt], 0,0,0);
        }
    }
    #pragma unroll
    for (int nt = 0; nt < 4; ++nt){
        int cc = nt*16 + lane16;
        #pragma unroll
        for (int i = 0; i < 4; ++i){
            int rr = w16 + quad*4 + i;
            float v2 = k2[nt][i] + sb[128 + cc];
            k2[nt][i] = v2;                        // keep o2k (with bias) in regs
            sXh[rr*72 + cc] = f2bf(v2);            // reuse sXh as o2k A-operand
        }
    }
    __syncthreads();

    // -------- layer 2b: o2n (consumes o2k per source bug) + softshrink --------
    f4 n2[4];
    #pragma unroll
    for (int nt = 0; nt < 4; ++nt) n2[nt] = (f4)0.0f;
    #pragma unroll
    for (int kq = 0; kq < 2; ++kq){
        short8 a1n = *(const short8*)&s1n[(w16 + lane16)*72 + kq*32 + quad*8];
        short8 a2k = *(const short8*)&sXh[(w16 + lane16)*72 + kq*32 + quad*8];
        #pragma unroll
        for (int nt = 0; nt < 4; ++nt){
            short8 wa = *(const short8*)&sW0[(nt*16 + lane16)*72 + kq*32 + quad*8];
            short8 wb = *(const short8*)&sW1[(nt*16 + lane16)*72 + kq*32 + quad*8];
            n2[nt] = __builtin_amdgcn_mfma_f32_16x16x32_bf16(a1n, wa, n2[nt], 0,0,0);
            n2[nt] = __builtin_amdgcn_mfma_f32_16x16x32_bf16(a2k, wb, n2[nt], 0,0,0);
        }
    }
    #pragma unroll
    for (int nt = 0; nt < 4; ++nt){
        int cc = nt*16 + lane16;
        #pragma unroll
        for (int i = 0; i < 4; ++i){
            int rr = w16 + quad*4 + i;
            int p = p0 + rr;
            float y = k2[nt][i] + n2[nt][i] + sb[192 + cc];
            float ay = fabsf(y) - 0.01f;           // softshrink lambda
            float r0 = ay > 0.f ? (y > 0.f ? ay : -ay) : 0.f;
            if (p < 64800) yout[(long long)p * 512 + kb*64 + cc] = f2bf(r0);
        }
    }
}

// ---------------- launch ----------------
extern "C" void kernel_launch(void* const* d_in, const int* in_sizes, int n_in,
                              void* d_out, int out_size, void* d_ws, size_t ws_size,
                              hipStream_t stream) {
    const float* x  = (const float*)d_in[0];
    const float* w1 = (const float*)d_in[1];
    const float* b1 = (const float*)d_in[2];
    const float* w2 = (const float*)d_in[3];
    const float* b2 = (const float*)d_in[4];
    float* out = (float*)d_out;

    u16* ws   = (u16*)d_ws;
    u16* casC = ws;                        // 262144
    u16* casW = casC + 262144;             // 360*384 = 138240
    u16* wts  = casW + 138240;             // 131072
    u16* bufT = wts  + 131072;             // 33177600 + 64 pad (T1 / y)
    u16* bufP = bufT + 33177664;           // 33177600 + 64 pad (xh / Z)
    // total ws ~133.8 MB

    prep<<<1024, 256, 0, stream>>>(w1, w2, casC, casW, wts);

    dim3 gBig(4, 507, 1);     // col-block fastest -> sibling blocks share A via L3
    dim3 gW(3, 4, 180);
    dim3 gM(1013, 8, 1);

    // A) T1[h][d][w] = (x . casC) transposed          (channel contraction)
    gemm_k<1,1,1><<<gBig, 256, 0, stream>>>(x, 512, 0, 64799,
                                            casC, 512, 0,
                                            bufT, 0, 64800, nullptr, 0.f, 16);
    // B) xh[(h,v)][d] = sum_w casW[v][w] * T1[h][d][w]  (width contraction)
    gemm_k<0,0,0><<<gW, 256, 0, stream>>>(casW, 384, 0, 359,
                                          bufT, 360, (long long)PL,
                                          bufP, (long long)PL, 360, nullptr, 0.f, 12);
    // C) block-MLP + softshrink: xh -> y
    mlp_k<<<gM, 256, 0, stream>>>(bufP, wts, b1, b2, bufT);
    // D) Z[h][d][w] = (y . casC) transposed
    gemm_k<0,1,1><<<gBig, 256, 0, stream>>>(bufT, 512, 0, 64799,
                                            casC, 512, 0,
                                            bufP, 0, 64800, nullptr, 0.f, 16);
    // E) out[(h,v)][d] = (sum_w casW[v][w] * Z[h][d][w]) / 184320 + x
    gemm_k<0,2,0><<<gW, 256, 0, stream>>>(casW, 384, 0, 359,
                                          bufP, 360, (long long)PL,
                                          out, (long long)PL, 360,
                                          x, 1.0f/184320.0f, 12);
}